// Round 2
// baseline (121.768 us; speedup 1.0000x reference)
//
#include <hip/hip_runtime.h>

// ParallelCNN: 4-branch masked conv bernoulli log-likelihood, B=16384, 28x28.
// Quad decomposition: planes a=s[2i,2j], b=s[2i,2j+1], c=s[2i+1,2j], d=s[2i+1,2j+1].
// Branch pm pixels: b0->a, b1->d, b2->b, b3->c. Masked conv taps per branch:
//   b0: none (position-only); b1: 4 corners (a-plane); b2: 2 horiz a + 2 vert d;
//   b3: 2 vert a + 2 horiz d + 4 corner b.
// Position-channel conv + bias is image-independent -> recomputed per block
// (196 quads x 4 pos-logits, ~150 FMA/lane, pos is L2-resident) — this removed
// the prep kernel + d_ws table round-trip (R1: harness d_ws poison dominates
// the measured window; our controllable share is the single main dispatch).

#define GRID    2048
#define TRIPS   2          // GRID * 4 waves * TRIPS = 16384 images, exact

__device__ __forceinline__ float sp_fast(float x) {
    // softplus; logits are small (|x| < ~3) so no range handling needed
    return __logf(1.0f + __expf(x));
}

// position-channel conv logit for branch x at pixel (h, ww), SAME zero pad
__device__ __forceinline__ float pos_logit(const float* __restrict__ pos,
                                           const float* __restrict__ w,
                                           const float* __restrict__ b,
                                           int x, int h, int ww) {
    float s = b[x];
    #pragma unroll
    for (int ky = 0; ky < 3; ++ky) {
        #pragma unroll
        for (int kx = 0; kx < 3; ++kx) {
            int hh = h + ky - 1, cc = ww + kx - 1;
            float p = (hh >= 0 && hh < 28 && cc >= 0 && cc < 28) ? pos[hh*28 + cc] : 0.0f;
            s = fmaf(w[x*18 + 9 + ky*3 + kx], p, s);   // weights[x][0][1][ky][kx]
        }
    }
    return s;
}

__global__ __launch_bounds__(256, 4)
void main_kernel(const float* __restrict__ samples,
                 const float* __restrict__ w,
                 const float* __restrict__ pos,
                 const float* __restrict__ b,
                 float* __restrict__ out) {
    // per-wave 4 parity planes, 16x16 each (1-elem zero halo all around)
    __shared__ float planes[4][4 * 256];   // 16 KB
    __shared__ float red[4];
    const int tid = threadIdx.x;
    const int wv = tid >> 6, ln = tid & 63;
    float* myP = planes[wv];

    // sample-channel tap weights: weights[x][0][0][ky][kx] = w[x*18 + ky*3 + kx]
    const float w1a = w[18+0], w1b = w[18+2], w1c = w[18+6], w1d = w[18+8]; // b1 corners
    const float w2l = w[36+3], w2r = w[36+5], w2u = w[36+1], w2n = w[36+7]; // b2
    const float w3u = w[54+1], w3n = w[54+7], w3l = w[54+3], w3r = w[54+5]; // b3 a/d
    const float w3a = w[54+0], w3b = w[54+2], w3c = w[54+6], w3e = w[54+8]; // b3 corner b

    // per-lane quad tables (quads t = k*64 + lane), computed in-kernel
    float C0[4], S0[4], P1[4], P2[4], P3[4];
    int oq[4]; bool qv[4];
    #pragma unroll
    for (int k = 0; k < 4; ++k) {
        int t = k*64 + ln;
        qv[k] = (t < 196);
        int i = t / 14, j = t - 14*i;
        oq[k] = (i+1)*16 + (j+1);
        C0[k]=S0[k]=P1[k]=P2[k]=P3[k]=0.f;
        if (qv[k]) {
            C0[k] = pos_logit(pos, w, b, 0, 2*i,   2*j);
            S0[k] = sp_fast(C0[k]);
            P1[k] = pos_logit(pos, w, b, 1, 2*i+1, 2*j+1);
            P2[k] = pos_logit(pos, w, b, 2, 2*i,   2*j+1);
            P3[k] = pos_logit(pos, w, b, 3, 2*i+1, 2*j);
        }
    }
    // float4 g covers row r=g/7, cols 4m..4m+3 (m=g%7) -> parity de-interleave target
    int wo[4];
    #pragma unroll
    for (int k = 0; k < 4; ++k) {
        int g = k*64 + ln;
        int r = g / 7, m = g - 7*r;
        wo[k] = ((r & 1) ? 512 : 0) + ((r >> 1) + 1)*16 + 2*m + 1;
    }

    // zero planes once; interior-only writes keep halos zero forever
    #pragma unroll
    for (int z = 0; z < 16; ++z) ((float*)planes)[z*256 + tid] = 0.0f;
    __syncthreads();

    // branch-0 softplus term is image-independent: fold TRIPS images out of the loop
    float s0sum = S0[0] + S0[1] + S0[2] + S0[3];   // invalid slots are 0
    float acc = -(float)TRIPS * s0sum;

    for (int trip = 0; trip < TRIPS; ++trip) {
        int img = (blockIdx.x + trip*GRID) * 4 + wv;
        const float4* src = (const float4*)(samples + (size_t)img * 784);
        #pragma unroll
        for (int k = 0; k < 4; ++k) {
            if (k < 3 || ln < 4) {             // 196 float4 = 3*64 + 4
                float4 v = src[k*64 + ln];
                float* p = myP + wo[k];
                p[0]   = v.x;  p[256] = v.y;   // a/c , b/d de-interleave
                p[1]   = v.z;  p[257] = v.w;
            }
        }
        __syncthreads();
        #pragma unroll
        for (int k = 0; k < 4; ++k) {
            if (qv[k]) {
                const int o = oq[k];
                float a00 = myP[o],        a01 = myP[o+1];
                float a10 = myP[o+16],     a11 = myP[o+17];
                float bl  = myP[256+o-1],  bij = myP[256+o];
                float bdl = myP[256+o+15], bdn = myP[256+o+16];
                float cij = myP[512+o];
                float dup = myP[768+o-16], dl  = myP[768+o-1], dij = myP[768+o];

                // branch 0 (pixel a): logit = C0 const; softplus already folded
                acc = fmaf(a00, C0[k], acc);
                // branch 1 (pixel d): 4 a-corners
                float L1 = P1[k];
                L1 = fmaf(w1a, a00, L1); L1 = fmaf(w1b, a01, L1);
                L1 = fmaf(w1c, a10, L1); L1 = fmaf(w1d, a11, L1);
                acc += fmaf(dij, L1, -sp_fast(L1));
                // branch 2 (pixel b): horiz a, vert d
                float L2 = P2[k];
                L2 = fmaf(w2l, a00, L2); L2 = fmaf(w2r, a01, L2);
                L2 = fmaf(w2u, dup, L2); L2 = fmaf(w2n, dij, L2);
                acc += fmaf(bij, L2, -sp_fast(L2));
                // branch 3 (pixel c): vert a, horiz d, corner b
                float L3 = P3[k];
                L3 = fmaf(w3u, a00, L3); L3 = fmaf(w3n, a10, L3);
                L3 = fmaf(w3l, dl,  L3); L3 = fmaf(w3r, dij, L3);
                L3 = fmaf(w3a, bl,  L3); L3 = fmaf(w3b, bij, L3);
                L3 = fmaf(w3c, bdl, L3); L3 = fmaf(w3e, bdn, L3);
                acc += fmaf(cij, L3, -sp_fast(L3));
            }
        }
        __syncthreads();
    }

    // reduce: wave butterfly -> per-wave LDS -> one atomic per block
    #pragma unroll
    for (int off = 32; off >= 1; off >>= 1)
        acc += __shfl_xor(acc, off, 64);
    if (ln == 0) red[wv] = acc;
    __syncthreads();
    if (tid == 0) atomicAdd(out, red[0] + red[1] + red[2] + red[3]);
}

extern "C" void kernel_launch(void* const* d_in, const int* in_sizes, int n_in,
                              void* d_out, int out_size, void* d_ws, size_t ws_size,
                              hipStream_t stream) {
    const float* samples  = (const float*)d_in[0];
    const float* position = (const float*)d_in[1];
    const float* weights  = (const float*)d_in[2];
    const float* biases   = (const float*)d_in[3];
    float* out = (float*)d_out;

    // d_out is re-poisoned to 0xAA before every timed launch; zero it for the atomics.
    hipMemsetAsync(out, 0, (size_t)out_size * sizeof(float), stream);
    main_kernel<<<GRID, 256, 0, stream>>>(samples, weights, position, biases, out);
}

// Round 3
// 95.365 us; speedup vs baseline: 1.2769x; 1.2769x over previous
//
#include <hip/hip_runtime.h>

// ParallelCNN: 4-branch masked conv bernoulli log-likelihood, B=16384, 28x28.
// Quad planes a=s[2i,2j], b=s[2i,2j+1], c=s[2i+1,2j], d=s[2i+1,2j+1].
// Branch pm pixels: b0->a (position-only logit), b1->d, b2->b, b3->c.
// Position-channel conv + bias -> per-quad tables, precomputed once into d_ws
// (the harness re-poisons d_ws every iteration whether we use it or not, so
// using it is free; R2 showed in-kernel recompute costs ~8 us of VALU).
// R2 post-mortem: 65% stall from (a) needless __syncthreads (planes are
// wave-private), (b) 2048 same-address atomicAdds. Both removed here:
// wave-synchronous LDS (same-wave DS ops are in-order on CDNA) + per-wave
// plain stores to ws, reduced by a tiny final kernel.

#define GRID 2048   // 4 waves/block, 2 images/wave -> 16384 images exact

__device__ __forceinline__ float sp_fast(float x) {
    // softplus; logits are small (|x| < ~3) so no range handling needed
    return __logf(1.0f + __expf(x));
}

// position-channel conv logit for branch x at pixel (h, ww), SAME zero pad
__device__ __forceinline__ float pos_logit(const float* __restrict__ pos,
                                           const float* __restrict__ w,
                                           const float* __restrict__ b,
                                           int x, int h, int ww) {
    float s = b[x];
    #pragma unroll
    for (int ky = 0; ky < 3; ++ky) {
        #pragma unroll
        for (int kx = 0; kx < 3; ++kx) {
            int hh = h + ky - 1, cc = ww + kx - 1;
            float p = (hh >= 0 && hh < 28 && cc >= 0 && cc < 28) ? pos[hh*28 + cc] : 0.0f;
            s = fmaf(w[x*18 + 9 + ky*3 + kx], p, s);   // weights[x][0][1][ky][kx]
        }
    }
    return s;
}

// tbl layout: 8 floats per quad t: [C0, S0=softplus(C0), P1, P2, P3, 0, 0, 0]
__global__ void prep_kernel(const float* __restrict__ pos,
                            const float* __restrict__ w,
                            const float* __restrict__ b,
                            float* __restrict__ tbl) {
    int u = blockIdx.x * blockDim.x + threadIdx.x;   // 4 blocks x 256 = 1024
    int t = u >> 2, x = u & 3;
    int i = t / 14, j = t % 14;
    bool valid = (t < 196);
    if (x == 0) {
        float C0 = 0.f, S0 = 0.f;
        if (valid) { C0 = pos_logit(pos, w, b, 0, 2*i, 2*j); S0 = sp_fast(C0); }
        tbl[t*8 + 0] = C0; tbl[t*8 + 1] = S0;
    } else if (x == 1) {
        tbl[t*8 + 2] = valid ? pos_logit(pos, w, b, 1, 2*i+1, 2*j+1) : 0.f;
        tbl[t*8 + 5] = 0.f;
    } else if (x == 2) {
        tbl[t*8 + 3] = valid ? pos_logit(pos, w, b, 2, 2*i,   2*j+1) : 0.f;
        tbl[t*8 + 6] = 0.f;
    } else {
        tbl[t*8 + 4] = valid ? pos_logit(pos, w, b, 3, 2*i+1, 2*j) : 0.f;
        tbl[t*8 + 7] = 0.f;
    }
}

__global__ __launch_bounds__(256, 4)
void main_kernel(const float* __restrict__ samples,
                 const float* __restrict__ w,
                 const float* __restrict__ tbl,
                 float* __restrict__ partial) {
    // wave-private 4 parity planes, 16x16 each (1-elem zero halo all around).
    // No __syncthreads anywhere: each wave reads/writes only planes[wv], and
    // same-wave DS ops execute in order; wave_barrier() pins compiler order.
    __shared__ float planes[4][1024];   // 16 KB
    const int tid = threadIdx.x;
    const int wv = tid >> 6, ln = tid & 63;
    float* myP = planes[wv];

    // sample-channel tap weights: weights[x][0][0][ky][kx] = w[x*18 + ky*3 + kx]
    const float w1a = w[18+0], w1b = w[18+2], w1c = w[18+6], w1d = w[18+8]; // b1 corners
    const float w2l = w[36+3], w2r = w[36+5], w2u = w[36+1], w2n = w[36+7]; // b2
    const float w3u = w[54+1], w3n = w[54+7], w3l = w[54+3], w3r = w[54+5]; // b3 a/d
    const float w3a = w[54+0], w3b = w[54+2], w3c = w[54+6], w3e = w[54+8]; // b3 corner b

    // per-lane quad tables (quads t = k*64 + lane) from ws
    float C0[4], P1[4], P2[4], P3[4], S0s = 0.f;
    int oq[4], wo[4]; bool qv[4];
    #pragma unroll
    for (int k = 0; k < 4; ++k) {
        int t = k*64 + ln;
        qv[k] = (t < 196);
        int i = t / 14, j = t - 14*i;
        oq[k] = (i+1)*16 + (j+1);
        const float4* t4 = (const float4*)(tbl + t*8);
        float4 lo = t4[0], hi = t4[1];
        C0[k] = lo.x; S0s += lo.y; P1[k] = lo.z; P2[k] = lo.w; P3[k] = hi.x;
        // float4 g covers row r=g/7, cols 4m..4m+3 -> parity de-interleave target
        int r = t / 7, m = t - 7*r;
        wo[k] = ((r & 1) ? 512 : 0) + ((r >> 1) + 1)*16 + 2*m + 1;
    }

    // zero own planes once (halo stays zero; interior rewritten per image)
    #pragma unroll
    for (int z = 0; z < 4; ++z)
        ((float4*)myP)[z*64 + ln] = float4{0.f, 0.f, 0.f, 0.f};

    // branch-0 softplus term is image-independent: fold both images out
    float acc = -2.0f * S0s;
    const int img0 = blockIdx.x * 8 + wv * 2;

    #pragma unroll
    for (int im = 0; im < 2; ++im) {
        const float4* src = (const float4*)(samples + (size_t)(img0 + im) * 784);
        float4 v[4];
        #pragma unroll
        for (int k = 0; k < 4; ++k)
            if (k < 3 || ln < 4) v[k] = src[k*64 + ln];   // 196 = 3*64 + 4
        __builtin_amdgcn_wave_barrier();    // prior image's reads stay before these writes
        #pragma unroll
        for (int k = 0; k < 4; ++k)
            if (k < 3 || ln < 4) {
                float* p = myP + wo[k];
                p[0]   = v[k].x;  p[256] = v[k].y;   // a/c , b/d de-interleave
                p[1]   = v[k].z;  p[257] = v[k].w;
            }
        __builtin_amdgcn_wave_barrier();    // writes stay before reads
        #pragma unroll
        for (int k = 0; k < 4; ++k) {
            if (qv[k]) {
                const int o = oq[k];
                float a00 = myP[o],        a01 = myP[o+1];
                float a10 = myP[o+16],     a11 = myP[o+17];
                float bl  = myP[256+o-1],  bij = myP[256+o];
                float bdl = myP[256+o+15], bdn = myP[256+o+16];
                float cij = myP[512+o];
                float dup = myP[768+o-16], dl  = myP[768+o-1], dij = myP[768+o];

                // branch 0 (pixel a): logit = C0 const; softplus already folded
                acc = fmaf(a00, C0[k], acc);
                // branch 1 (pixel d): 4 a-corners
                float L1 = P1[k];
                L1 = fmaf(w1a, a00, L1); L1 = fmaf(w1b, a01, L1);
                L1 = fmaf(w1c, a10, L1); L1 = fmaf(w1d, a11, L1);
                acc += fmaf(dij, L1, -sp_fast(L1));
                // branch 2 (pixel b): horiz a, vert d
                float L2 = P2[k];
                L2 = fmaf(w2l, a00, L2); L2 = fmaf(w2r, a01, L2);
                L2 = fmaf(w2u, dup, L2); L2 = fmaf(w2n, dij, L2);
                acc += fmaf(bij, L2, -sp_fast(L2));
                // branch 3 (pixel c): vert a, horiz d, corner b
                float L3 = P3[k];
                L3 = fmaf(w3u, a00, L3); L3 = fmaf(w3n, a10, L3);
                L3 = fmaf(w3l, dl,  L3); L3 = fmaf(w3r, dij, L3);
                L3 = fmaf(w3a, bl,  L3); L3 = fmaf(w3b, bij, L3);
                L3 = fmaf(w3c, bdl, L3); L3 = fmaf(w3e, bdn, L3);
                acc += fmaf(cij, L3, -sp_fast(L3));
            }
        }
    }

    // wave butterfly -> one plain store per wave (no atomics, no barrier)
    #pragma unroll
    for (int off = 32; off >= 1; off >>= 1)
        acc += __shfl_xor(acc, off, 64);
    if (ln == 0) partial[blockIdx.x * 4 + wv] = acc;
}

// reduce 8192 per-wave partials -> out[0]; overwrites the 0xAA poison directly
__global__ void final_kernel(const float* __restrict__ partial,
                             float* __restrict__ out) {
    __shared__ float red[4];
    const int tid = threadIdx.x;
    float s = 0.f;
    #pragma unroll
    for (int i = 0; i < 32; ++i) s += partial[i*256 + tid];
    #pragma unroll
    for (int off = 32; off >= 1; off >>= 1) s += __shfl_xor(s, off, 64);
    if ((tid & 63) == 0) red[tid >> 6] = s;
    __syncthreads();
    if (tid == 0) out[0] = red[0] + red[1] + red[2] + red[3];
}

extern "C" void kernel_launch(void* const* d_in, const int* in_sizes, int n_in,
                              void* d_out, int out_size, void* d_ws, size_t ws_size,
                              hipStream_t stream) {
    const float* samples  = (const float*)d_in[0];
    const float* position = (const float*)d_in[1];
    const float* weights  = (const float*)d_in[2];
    const float* biases   = (const float*)d_in[3];
    float* ws_f = (float*)d_ws;
    float* tbl     = ws_f;          // 1568 floats
    float* partial = ws_f + 2048;   // 8192 floats
    float* out = (float*)d_out;

    prep_kernel<<<4, 256, 0, stream>>>(position, weights, biases, tbl);
    main_kernel<<<GRID, 256, 0, stream>>>(samples, weights, tbl, partial);
    final_kernel<<<1, 256, 0, stream>>>(partial, out);
}